// Round 2
// baseline (239.665 us; speedup 1.0000x reference)
//
#include <hip/hip_runtime.h>
#include <hip/hip_bf16.h>

#define GLOBAL_AS __attribute__((address_space(1)))
#define LDS_AS    __attribute__((address_space(3)))

typedef __bf16 bf16x8 __attribute__((ext_vector_type(8)));
typedef float  f32x4  __attribute__((ext_vector_type(4)));

constexpr int BATCH = 8192;           // M
constexpr int IN    = 1024;
constexpr int OUT   = 1024;           // N
constexpr int KDIM  = IN * 4;         // 4096 (4 "powers" per input)
constexpr int TM = 128, TN = 128, BK = 32;
constexpr int SAROW = 40;             // padded sA row stride (elems): 80 B -> 2-way (free) read conflicts

// round-to-nearest-even float -> bf16 bits (inputs finite)
__device__ __forceinline__ unsigned short f2bf(float f) {
    union { float f; unsigned u; } v; v.f = f;
    unsigned r = v.u + 0x7fffu + ((v.u >> 16) & 1u);
    return (unsigned short)(r >> 16);
}
__device__ __forceinline__ unsigned pk(unsigned short a, unsigned short b) {
    return (unsigned)a | ((unsigned)b << 16);
}

// Merged: B_big[o, 4i+k] = {W[o,i], C[o,i,1..3]} bf16, and
// be[o] = bias[o] + sum_i C[o,i,0] (exact fp32). One block per o.
__global__ __launch_bounds__(256) void prep_w(const float* __restrict__ W,
                                              const float* __restrict__ C,
                                              const float* __restrict__ bias,
                                              unsigned short* __restrict__ Bb,
                                              float* __restrict__ be) {
    const int o = blockIdx.x, t = threadIdx.x;
    const int i0 = t * 4;                                   // 4 consecutive i per thread
    const float4* c4 = reinterpret_cast<const float4*>(C + ((size_t)o * IN + i0) * 4);
    float4 w4 = *reinterpret_cast<const float4*>(W + (size_t)o * IN + i0);
    float wv[4] = {w4.x, w4.y, w4.z, w4.w};
    float s = 0.f;
    unsigned d[8];
#pragma unroll
    for (int j = 0; j < 4; ++j) {
        float4 c = c4[j];
        s += c.x;                                           // x^0 term -> bias
        d[2*j]   = pk(f2bf(wv[j]), f2bf(c.y));
        d[2*j+1] = pk(f2bf(c.z),   f2bf(c.w));
    }
    uint4* dst = reinterpret_cast<uint4*>(Bb + (size_t)o * KDIM + i0 * 4);
    dst[0] = make_uint4(d[0], d[1], d[2], d[3]);
    dst[1] = make_uint4(d[4], d[5], d[6], d[7]);
#pragma unroll
    for (int off = 32; off > 0; off >>= 1) s += __shfl_down(s, off, 64);
    __shared__ float red[4];
    if ((t & 63) == 0) red[t >> 6] = s;
    __syncthreads();
    if (t == 0) be[o] = bias[o] + red[0] + red[1] + red[2] + red[3];
}

// out = [silu(x),x,x^2,x^3](8192 x 4096) * B_big(1024 x 4096)^T + be.
// A is built in-register from x and staged via ds_write_b128 (padded rows);
// B staged via global_load_lds with XOR-swizzled 16B groups.
__global__ __launch_bounds__(256) void gemm_kan(
        const float* __restrict__ x,
        const unsigned short* __restrict__ Bb,
        const float* __restrict__ be,
        float* __restrict__ out) {
    __shared__ unsigned short sA[TM * SAROW];   // 10 KB (padded)
    __shared__ unsigned short sB[TN * BK];      // 8 KB (layout fixed by global_load_lds)

    const int t    = threadIdx.x;
    const int bn   = blockIdx.x;                // 0..7
    const int bm   = blockIdx.y;                // 0..63
    const int lane = t & 63;
    const int wave = t >> 6;
    const int wr   = wave >> 1;                 // 64-row half
    const int wc   = wave & 1;                  // 64-col half
    const int l15  = lane & 15;
    const int quad = lane >> 4;

    // ---- A staging: thread t covers x[row = t>>1, 4 floats at half=(t&1)] per K-chunk
    const int rA = t >> 1;
    const int hA = t & 1;
    const float* px = x + (size_t)(bm * TM + rA) * IN + hA * 4;
    const int wAoff = rA * SAROW + hA * 16;     // elem offset of this thread's 16 bf16

    // ---- B staging: dest slot g_dst = t&3; source group = g_dst ^ (row&3) (XOR swizzle)
    const int rowS = t >> 2;
    const int colS = ((t & 3) ^ (rowS & 3)) * 8;
    const unsigned short* pb0 = Bb + (size_t)(bn * TN + rowS) * KDIM + colS;
    const unsigned short* pb1 = pb0 + (size_t)64 * KDIM;

    f32x4 acc[4][4];
    const f32x4 zero = {0.f, 0.f, 0.f, 0.f};
#pragma unroll
    for (int i = 0; i < 4; ++i)
#pragma unroll
        for (int j = 0; j < 4; ++j) acc[i][j] = zero;

    const int aoff = (wr * 64 + l15) * SAROW + quad * 8;                 // + mi*16*SAROW
    const int boff = (wc * 64 + l15) * BK + ((quad ^ (l15 & 3)) * 8);    // + ni*16*BK

    for (int k0 = 0; k0 < KDIM; k0 += BK) {
        // x load for this K-chunk (to registers; overlaps prior compute)
        float4 xv4 = *reinterpret_cast<const float4*>(px + (k0 >> 2));

        __syncthreads();   // prior iteration's LDS reads done

        __builtin_amdgcn_global_load_lds((const GLOBAL_AS void*)(pb0 + k0),
                                         (LDS_AS void*)(sB + t * 8), 16, 0, 0);
        __builtin_amdgcn_global_load_lds((const GLOBAL_AS void*)(pb1 + k0),
                                         (LDS_AS void*)(sB + 2048 + t * 8), 16, 0, 0);

        // compute {silu, x, x^2, x^3} for 4 x-values -> 16 bf16 -> 2x ds_write_b128
        float e[4] = {xv4.x, xv4.y, xv4.z, xv4.w};
        unsigned d[8];
#pragma unroll
        for (int j = 0; j < 4; ++j) {
            float xv = e[j];
            float sl = xv / (1.0f + __expf(-xv));
            float x2 = xv * xv;
            d[2*j]   = pk(f2bf(sl), f2bf(xv));
            d[2*j+1] = pk(f2bf(x2), f2bf(x2 * xv));
        }
        uint4* dstA = reinterpret_cast<uint4*>(sA + wAoff);
        dstA[0] = make_uint4(d[0], d[1], d[2], d[3]);
        dstA[1] = make_uint4(d[4], d[5], d[6], d[7]);

        __syncthreads();   // staging complete

        bf16x8 af[4], bv[4];
#pragma unroll
        for (int i = 0; i < 4; ++i)
            af[i] = *reinterpret_cast<const bf16x8*>(sA + aoff + i * 16 * SAROW);
#pragma unroll
        for (int i = 0; i < 4; ++i)
            bv[i] = *reinterpret_cast<const bf16x8*>(sB + boff + i * 16 * BK);

#pragma unroll
        for (int mi = 0; mi < 4; ++mi)
#pragma unroll
            for (int ni = 0; ni < 4; ++ni)
                acc[mi][ni] = __builtin_amdgcn_mfma_f32_16x16x32_bf16(
                    af[mi], bv[ni], acc[mi][ni], 0, 0, 0);
    }

    // epilogue: C/D layout col = lane&15, row = quad*4 + reg
    float bev[4];
#pragma unroll
    for (int ni = 0; ni < 4; ++ni)
        bev[ni] = be[bn * TN + wc * 64 + ni * 16 + l15];

#pragma unroll
    for (int mi = 0; mi < 4; ++mi) {
        const int grow = bm * TM + wr * 64 + mi * 16 + quad * 4;
#pragma unroll
        for (int ni = 0; ni < 4; ++ni) {
            const int gcol = bn * TN + wc * 64 + ni * 16 + l15;
            float* po = out + (size_t)grow * OUT + gcol;
#pragma unroll
            for (int r = 0; r < 4; ++r)
                po[(size_t)r * OUT] = acc[mi][ni][r] + bev[ni];
        }
    }
}

extern "C" void kernel_launch(void* const* d_in, const int* in_sizes, int n_in,
                              void* d_out, int out_size, void* d_ws, size_t ws_size,
                              hipStream_t stream) {
    const float* x    = (const float*)d_in[0];   // [8192,1024]
    const float* W    = (const float*)d_in[1];   // [1024,1024]
    const float* C    = (const float*)d_in[2];   // [1024,1024,4]
    const float* bias = (const float*)d_in[3];   // [1024]
    float* out = (float*)d_out;

    unsigned short* Bb = (unsigned short*)d_ws;            // 1024*4096 bf16 = 8 MB
    float*          be = (float*)(Bb + (size_t)OUT * KDIM);// 4 KB

    prep_w<<<dim3(OUT), dim3(256), 0, stream>>>(W, C, bias, Bb, be);

    dim3 grid(OUT / TN, BATCH / TM);   // 8 x 64 = 512 blocks
    gemm_kan<<<grid, dim3(256), 0, stream>>>(x, Bb, be, out);
}

// Round 3
// 190.789 us; speedup vs baseline: 1.2562x; 1.2562x over previous
//
#include <hip/hip_runtime.h>
#include <hip/hip_bf16.h>

#define GLOBAL_AS __attribute__((address_space(1)))
#define LDS_AS    __attribute__((address_space(3)))

typedef __bf16 bf16x8 __attribute__((ext_vector_type(8)));
typedef float  f32x4  __attribute__((ext_vector_type(4)));

constexpr int BATCH = 8192;           // M
constexpr int IN    = 1024;
constexpr int OUT   = 1024;           // N
constexpr int KDIM  = IN * 4;         // 4096 (4 "powers" per input)
constexpr int TM = 128, TN = 128, BK = 32;

// round-to-nearest-even float -> bf16 bits (inputs finite)
__device__ __forceinline__ unsigned short f2bf(float f) {
    union { float f; unsigned u; } v; v.f = f;
    unsigned r = v.u + 0x7fffu + ((v.u >> 16) & 1u);
    return (unsigned short)(r >> 16);
}
__device__ __forceinline__ unsigned pk(unsigned short a, unsigned short b) {
    return (unsigned)a | ((unsigned)b << 16);
}

// A_big[b, 4i+k] = {silu(x), x, x^2, x^3} bf16. One thread per float4 of x.
__global__ void prep_a(const float* __restrict__ x, unsigned short* __restrict__ A) {
    int idx = blockIdx.x * 256 + threadIdx.x;          // 8192*1024/4 threads
    float4 v = reinterpret_cast<const float4*>(x)[idx];
    float e0[4] = {v.x, v.y, v.z, v.w};
    unsigned short o[16];
#pragma unroll
    for (int j = 0; j < 4; ++j) {
        float xv = e0[j];
        float s  = xv / (1.0f + __expf(-xv));
        float x2 = xv * xv;
        o[4*j+0] = f2bf(s);
        o[4*j+1] = f2bf(xv);
        o[4*j+2] = f2bf(x2);
        o[4*j+3] = f2bf(x2 * xv);
    }
    uint4 d0 = make_uint4(pk(o[0],o[1]),  pk(o[2],o[3]),   pk(o[4],o[5]),   pk(o[6],o[7]));
    uint4 d1 = make_uint4(pk(o[8],o[9]),  pk(o[10],o[11]), pk(o[12],o[13]), pk(o[14],o[15]));
    uint4* dst = reinterpret_cast<uint4*>(A) + (size_t)idx * 2;
    dst[0] = d0;
    dst[1] = d1;
}

// Merged: B_big[o, 4i+k] = {W[o,i], C[o,i,1..3]} bf16, and
// be[o] = bias[o] + sum_i C[o,i,0] (exact fp32). One block per o.
__global__ __launch_bounds__(256) void prep_w(const float* __restrict__ W,
                                              const float* __restrict__ C,
                                              const float* __restrict__ bias,
                                              unsigned short* __restrict__ Bb,
                                              float* __restrict__ be) {
    const int o = blockIdx.x, t = threadIdx.x;
    const int i0 = t * 4;
    const float4* c4 = reinterpret_cast<const float4*>(C + ((size_t)o * IN + i0) * 4);
    float4 w4 = *reinterpret_cast<const float4*>(W + (size_t)o * IN + i0);
    float wv[4] = {w4.x, w4.y, w4.z, w4.w};
    float s = 0.f;
    unsigned d[8];
#pragma unroll
    for (int j = 0; j < 4; ++j) {
        float4 c = c4[j];
        s += c.x;                                      // x^0 term -> bias
        d[2*j]   = pk(f2bf(wv[j]), f2bf(c.y));
        d[2*j+1] = pk(f2bf(c.z),   f2bf(c.w));
    }
    uint4* dst = reinterpret_cast<uint4*>(Bb + (size_t)o * KDIM + i0 * 4);
    dst[0] = make_uint4(d[0], d[1], d[2], d[3]);
    dst[1] = make_uint4(d[4], d[5], d[6], d[7]);
#pragma unroll
    for (int off = 32; off > 0; off >>= 1) s += __shfl_down(s, off, 64);
    __shared__ float red[4];
    if ((t & 63) == 0) red[t >> 6] = s;
    __syncthreads();
    if (t == 0) be[o] = bias[o] + red[0] + red[1] + red[2] + red[3];
}

// C = A_big(8192x4096) * B_big(1024x4096)^T + be.
// XCD-aware block remap: each XCD owns 8 bm-stripes (A read once per XCD).
// LDS layout XOR-swizzled via SOURCE k-group permutation (global_load_lds
// dst must stay lane-contiguous): slot (row, c) holds kgroup c^((row>>1)&3).
__global__ __launch_bounds__(256) void gemm_kan(
        const unsigned short* __restrict__ Ab,
        const unsigned short* __restrict__ Bb,
        const float* __restrict__ be,
        float* __restrict__ out) {
    __shared__ unsigned short sA[TM * BK];   // 8 KB
    __shared__ unsigned short sB[TN * BK];   // 8 KB

    const int t   = threadIdx.x;
    const int l   = blockIdx.x;              // 0..511
    const int bm  = (l & 7) * 8 + ((l >> 3) & 7);   // XCD (l&7) owns bm 8x..8x+7
    const int bn  = l >> 6;                  // 0..7
    const int lane = t & 63;
    const int wave = t >> 6;
    const int wr   = wave >> 1;              // 64-row half
    const int wc   = wave & 1;               // 64-col half
    const int l15  = lane & 15;
    const int quad = lane >> 4;

    // staging: thread t fetches (row = t>>2, kgroup = (t&3)^((row>>1)&3)), dst = t*16B
    const int rowS = t >> 2;
    const int gsw  = (t & 3) ^ ((t >> 3) & 3);
    const int colS = gsw * 8;

    const unsigned short* pa0 = Ab + (size_t)(bm * TM + rowS) * KDIM + colS;
    const unsigned short* pa1 = pa0 + (size_t)64 * KDIM;
    const unsigned short* pb0 = Bb + (size_t)(bn * TN + rowS) * KDIM + colS;
    const unsigned short* pb1 = pb0 + (size_t)64 * KDIM;

    f32x4 acc[4][4];
    const f32x4 zero = {0.f, 0.f, 0.f, 0.f};
#pragma unroll
    for (int i = 0; i < 4; ++i)
#pragma unroll
        for (int j = 0; j < 4; ++j) acc[i][j] = zero;

    // read: slot c = quad ^ ((row>>1)&3); row bases are multiples of 16 so
    // ((row>>1)&3) == ((l15>>1)&3)
    const int xq   = (quad ^ ((l15 >> 1) & 3)) * 8;
    const int aoff = (wr * 64 + l15) * BK + xq;   // + mi*16*BK
    const int boff = (wc * 64 + l15) * BK + xq;   // + ni*16*BK

    for (int k0 = 0; k0 < KDIM; k0 += BK) {
        __syncthreads();
        __builtin_amdgcn_global_load_lds((const GLOBAL_AS void*)(pa0 + k0),
                                         (LDS_AS void*)(sA + t * 8), 16, 0, 0);
        __builtin_amdgcn_global_load_lds((const GLOBAL_AS void*)(pa1 + k0),
                                         (LDS_AS void*)(sA + 2048 + t * 8), 16, 0, 0);
        __builtin_amdgcn_global_load_lds((const GLOBAL_AS void*)(pb0 + k0),
                                         (LDS_AS void*)(sB + t * 8), 16, 0, 0);
        __builtin_amdgcn_global_load_lds((const GLOBAL_AS void*)(pb1 + k0),
                                         (LDS_AS void*)(sB + 2048 + t * 8), 16, 0, 0);
        __syncthreads();

        bf16x8 af[4], bv[4];
#pragma unroll
        for (int i = 0; i < 4; ++i)
            af[i] = *reinterpret_cast<const bf16x8*>(sA + aoff + i * 16 * BK);
#pragma unroll
        for (int i = 0; i < 4; ++i)
            bv[i] = *reinterpret_cast<const bf16x8*>(sB + boff + i * 16 * BK);

#pragma unroll
        for (int mi = 0; mi < 4; ++mi)
#pragma unroll
            for (int ni = 0; ni < 4; ++ni)
                acc[mi][ni] = __builtin_amdgcn_mfma_f32_16x16x32_bf16(
                    af[mi], bv[ni], acc[mi][ni], 0, 0, 0);
    }

    // epilogue: C/D layout col = lane&15, row = quad*4 + reg
    float bev[4];
#pragma unroll
    for (int ni = 0; ni < 4; ++ni)
        bev[ni] = be[bn * TN + wc * 64 + ni * 16 + l15];

#pragma unroll
    for (int mi = 0; mi < 4; ++mi) {
        const int grow = bm * TM + wr * 64 + mi * 16 + quad * 4;
#pragma unroll
        for (int ni = 0; ni < 4; ++ni) {
            const int gcol = bn * TN + wc * 64 + ni * 16 + l15;
            float* po = out + (size_t)grow * OUT + gcol;
#pragma unroll
            for (int r = 0; r < 4; ++r)
                po[(size_t)r * OUT] = acc[mi][ni][r] + bev[ni];
        }
    }
}

extern "C" void kernel_launch(void* const* d_in, const int* in_sizes, int n_in,
                              void* d_out, int out_size, void* d_ws, size_t ws_size,
                              hipStream_t stream) {
    const float* x    = (const float*)d_in[0];   // [8192,1024]
    const float* W    = (const float*)d_in[1];   // [1024,1024]
    const float* C    = (const float*)d_in[2];   // [1024,1024,4]
    const float* bias = (const float*)d_in[3];   // [1024]
    float* out = (float*)d_out;

    unsigned short* Ab = (unsigned short*)d_ws;                    // 64 MB
    unsigned short* Bb = Ab + (size_t)BATCH * KDIM;                // 8 MB
    float*          be = (float*)(Bb + (size_t)OUT * KDIM);        // 4 KB

    prep_a<<<dim3(BATCH * IN / 4 / 256), dim3(256), 0, stream>>>(x, Ab);
    prep_w<<<dim3(OUT), dim3(256), 0, stream>>>(W, C, bias, Bb, be);

    gemm_kan<<<dim3(512), dim3(256), 0, stream>>>(Ab, Bb, be, out);
}